// Round 1
// 2798.722 us; speedup vs baseline: 4.0660x; 4.0660x over previous
//
#include <hip/hip_runtime.h>

// ---------------------------------------------------------------------------
// EdgeTransition — Round 6: L1-bound fix.
//  (1) Fold nb_i/nb_j layer-0 contributions into precomputed Pb/Q  (-28.6% FMA)
//  (2) Stage weights in LDS via double-buffered global_load_lds (2-phase)
//  (3) Register tile TM=8 x TN=6: 0.5 B LDS per FMA (budget 1.0) -> VALU-bound
// Block: 32 rows x 256 threads (4 waves). ct=t&63 covers 384 cols (6/lane),
// mth=t>>6 covers 32 rows (8/lane). LDS: A(49.7K)+B(49.7K)+Wdbuf(48K) ~148K,
// 1 block/CU.
// ---------------------------------------------------------------------------

#define ROWS 32
#define PF 388  // fp32 LDS pitch (384+4)
#define TM 8
#define TN 6

union F4 { float4 v; float f[4]; };
union F2 { float2 v; float f[2]; };

__device__ __forceinline__ void async_cp16(const float* g, float* l) {
  __builtin_amdgcn_global_load_lds(
      (const __attribute__((address_space(1))) void*)g,
      (__attribute__((address_space(3))) void*)l, 16, 0, 0);
}

// stage nchunk 1024B-chunks: contiguous global -> contiguous LDS (4 waves coop)
__device__ __forceinline__ void stage_tile(const float* __restrict__ g,
                                           float* l, int nchunk, int t) {
  const int lane = t & 63, wid = t >> 6;
  for (int c = wid; c < nchunk; c += 4)
    async_cp16(g + c * 256 + lane * 4, l + c * 256);  // lds dest wave-uniform
}

// one 16-deep K-tile of a 384-wide trunk layer: acc[8][6] += A[8][16]*W[16][6]
__device__ __forceinline__ void trunk_tile(const float* __restrict__ src,
                                           int koff,
                                           const float* __restrict__ wt,
                                           int ct, int mr, float acc[TM][TN]) {
  const float* wbase = wt + ct * TN;
  for (int kk = 0; kk < 16; kk += 4) {
    F4 a[TM];
#pragma unroll
    for (int r = 0; r < TM; r++)
      a[r].v = *(const float4*)(src + (mr + r) * PF + koff + kk);
#pragma unroll
    for (int ks = 0; ks < 4; ks++) {
      const float* wr = wbase + (kk + ks) * 384;
      F2 w0, w1, w2;
      w0.v = *(const float2*)(wr + 0);
      w1.v = *(const float2*)(wr + 2);
      w2.v = *(const float2*)(wr + 4);
      const float wv0 = w0.f[0], wv1 = w0.f[1], wv2 = w1.f[0];
      const float wv3 = w1.f[1], wv4 = w2.f[0], wv5 = w2.f[1];
#pragma unroll
      for (int r = 0; r < TM; r++) {
        const float ak = a[r].f[ks];
        acc[r][0] += ak * wv0;
        acc[r][1] += ak * wv1;
        acc[r][2] += ak * wv2;
        acc[r][3] += ak * wv3;
        acc[r][4] += ak * wv4;
        acc[r][5] += ak * wv5;
      }
    }
  }
}

// ---------------------------------------------------------------------------
// nb[i][c] = node[i,:256] @ w_init[:,c] + b_init[c]   (512 x 128)
// ---------------------------------------------------------------------------
__global__ void node_proj(const float* __restrict__ node,
                          const float* __restrict__ w,
                          const float* __restrict__ b,
                          float* __restrict__ nb) {
  __shared__ float sn[256];
  int i = blockIdx.x;
  int t = threadIdx.x;  // 128 threads
  sn[t] = node[i * 256 + t];
  sn[t + 128] = node[i * 256 + t + 128];
  __syncthreads();
  float acc = b[t];
  for (int k = 0; k < 256; k++) acc += sn[k] * w[k * 128 + t];
  nb[i * 128 + t] = acc;
}

// ---------------------------------------------------------------------------
// Pb[j][c] = b0[c] + nb[j] @ W0[128:256, c]   (i-part rows of W0, bias folded)
// Qm[j][c] =          nb[j] @ W0[256:384, c]  (j-part rows of W0)
// ---------------------------------------------------------------------------
__global__ void pq_proj(const float* __restrict__ nb,
                        const float* __restrict__ w0,
                        const float* __restrict__ b0,
                        float* __restrict__ Pb, float* __restrict__ Qm) {
  __shared__ float sn[128];
  const int j = blockIdx.x, t = threadIdx.x;  // 384 threads
  if (t < 128) sn[t] = nb[j * 128 + t];
  __syncthreads();
  float ap = b0[t], aq = 0.0f;
  for (int k = 0; k < 128; k++) {
    const float nk = sn[k];
    ap += nk * w0[(128 + k) * 384 + t];
    aq += nk * w0[(256 + k) * 384 + t];
  }
  Pb[j * 384 + t] = ap;
  Qm[j * 384 + t] = aq;
}

// ---------------------------------------------------------------------------
// fused edge kernel
// ---------------------------------------------------------------------------
__global__ __launch_bounds__(256, 1) void edge_fused(
    const float* __restrict__ edge, const float* __restrict__ nbf,
    const float* __restrict__ Pb, const float* __restrict__ Qm,
    const float* __restrict__ w0, const float* __restrict__ w1,
    const float* __restrict__ b1v, const float* __restrict__ wf,
    const float* __restrict__ bfin, const float* __restrict__ lng,
    const float* __restrict__ lnb, float* __restrict__ out) {
  __shared__ __align__(16) float Abuf[ROWS * PF];      // edge cols, then t1+h
  __shared__ __align__(16) float Bbuf[ROWS * PF];      // t0
  __shared__ __align__(16) float Wt[2][16 * 384];      // W tile double-buffer
  __shared__ __align__(16) float snbi[128];            // nb_i

  const int t = threadIdx.x;
  const int ct = t & 63;            // 64 col-groups x 6 cols
  const int mr = (t >> 6) * TM;     // 4 waves x 8 rows
  const int r0 = blockIdx.x * ROWS;
  const int i_node = r0 >> 9, j0 = r0 & 511;

  // ---- prologue: edge rows -> Abuf[.][0:128]; nb_i -> snbi ----
  {
    const int row = t >> 3, q = t & 7;  // 32 rows x 8 threads x 16 floats
    const float* ep = edge + (size_t)(r0 + row) * 128 + q * 16;
    float* ap = Abuf + row * PF + q * 16;
#pragma unroll
    for (int u = 0; u < 4; u++)
      *(float4*)(ap + u * 4) = *(const float4*)(ep + u * 4);
  }
  if (t < 32)
    *(float4*)(snbi + t * 4) = *(const float4*)(nbf + i_node * 128 + t * 4);

  stage_tile(w0, Wt[0], 24, t);  // L0 tile 0 (async)

  // ---- acc init: Pb[i] + Q[j0+row]  (b0 already folded into Pb) ----
  float acc[TM][TN];
  {
    const float* pr = Pb + i_node * 384 + ct * 6;
    F2 p0, p1, p2;
    p0.v = *(const float2*)(pr + 0);
    p1.v = *(const float2*)(pr + 2);
    p2.v = *(const float2*)(pr + 4);
#pragma unroll
    for (int r = 0; r < TM; r++) {
      const float* qr = Qm + (size_t)(j0 + mr + r) * 384 + ct * 6;
      F2 q0, q1, q2;
      q0.v = *(const float2*)(qr + 0);
      q1.v = *(const float2*)(qr + 2);
      q2.v = *(const float2*)(qr + 4);
      acc[r][0] = p0.f[0] + q0.f[0];
      acc[r][1] = p0.f[1] + q0.f[1];
      acc[r][2] = p1.f[0] + q1.f[0];
      acc[r][3] = p1.f[1] + q1.f[1];
      acc[r][4] = p2.f[0] + q2.f[0];
      acc[r][5] = p2.f[1] + q2.f[1];
    }
  }

  // ---- layer 0: K=128 (edge cols only), 8 tiles ----
  for (int kt = 0; kt < 8; kt++) {
    __syncthreads();  // tile kt staged (drains vmcnt before barrier)
    if (kt < 7) stage_tile(w0 + (kt + 1) * 6144, Wt[(kt + 1) & 1], 24, t);
    trunk_tile(Abuf, kt * 16, Wt[kt & 1], ct, mr, acc);
  }

  // ---- L0 epilogue: relu -> Bbuf; prefetch L1 tile 0 ----
  stage_tile(w1, Wt[0], 24, t);  // L0's last tile used Wt[1]; safe
#pragma unroll
  for (int r = 0; r < TM; r++) {
    float* dr = Bbuf + (mr + r) * PF + ct * 6;
    F2 e0, e1, e2;
    e0.f[0] = fmaxf(acc[r][0], 0.0f);
    e0.f[1] = fmaxf(acc[r][1], 0.0f);
    e1.f[0] = fmaxf(acc[r][2], 0.0f);
    e1.f[1] = fmaxf(acc[r][3], 0.0f);
    e2.f[0] = fmaxf(acc[r][4], 0.0f);
    e2.f[1] = fmaxf(acc[r][5], 0.0f);
    *(float2*)(dr + 0) = e0.v;
    *(float2*)(dr + 2) = e1.v;
    *(float2*)(dr + 4) = e2.v;
  }

  // re-init acc with b1 (folded)
  {
    const float* br = b1v + ct * 6;
    F2 c0, c1, c2;
    c0.v = *(const float2*)(br + 0);
    c1.v = *(const float2*)(br + 2);
    c2.v = *(const float2*)(br + 4);
#pragma unroll
    for (int r = 0; r < TM; r++) {
      acc[r][0] = c0.f[0]; acc[r][1] = c0.f[1];
      acc[r][2] = c1.f[0]; acc[r][3] = c1.f[1];
      acc[r][4] = c2.f[0]; acc[r][5] = c2.f[1];
    }
  }

  // ---- layer 1: K=384 from Bbuf, 24 tiles ----
  for (int kt = 0; kt < 24; kt++) {
    __syncthreads();
    if (kt < 23) stage_tile(w1 + (kt + 1) * 6144, Wt[(kt + 1) & 1], 24, t);
    trunk_tile(Bbuf, kt * 16, Wt[kt & 1], ct, mr, acc);
  }

  stage_tile(wf, Wt[0], 16, t);  // final tile 0 (L1's last tile used Wt[1])

  // ---- L1 epilogue: relu + residual h -> Abuf (in place, own fragment) ----
#pragma unroll
  for (int r = 0; r < TM; r++) {
    const int row = mr + r;
    float* dr = Abuf + row * PF;
    const float* njr = nbf + (size_t)(j0 + row) * 128;
#pragma unroll
    for (int c = 0; c < TN; c++) {
      const int col = ct * 6 + c;
      const float hv = (col < 128) ? dr[col]
                     : (col < 256) ? snbi[col - 128]
                                   : njr[col - 256];
      dr[col] = fmaxf(acc[r][c], 0.0f) + hv;
    }
  }

  // ---- final: K=384, N=128 from Abuf; 12 tiles of KT=32 ----
  float af[TM][2];
  {
    F2 b2;
    b2.v = *(const float2*)(bfin + ct * 2);
#pragma unroll
    for (int r = 0; r < TM; r++) { af[r][0] = b2.f[0]; af[r][1] = b2.f[1]; }
  }
  for (int ft = 0; ft < 12; ft++) {
    __syncthreads();
    if (ft < 11) stage_tile(wf + (ft + 1) * 4096, Wt[(ft + 1) & 1], 16, t);
    const float* wtc = Wt[ft & 1] + ct * 2;
    const int koff = ft * 32;
    for (int kk = 0; kk < 32; kk += 4) {
      F4 a[TM];
#pragma unroll
      for (int r = 0; r < TM; r++)
        a[r].v = *(const float4*)(Abuf + (mr + r) * PF + koff + kk);
#pragma unroll
      for (int ks = 0; ks < 4; ks++) {
        F2 wv;
        wv.v = *(const float2*)(wtc + (kk + ks) * 128);
#pragma unroll
        for (int r = 0; r < TM; r++) {
          const float ak = a[r].f[ks];
          af[r][0] += ak * wv.f[0];
          af[r][1] += ak * wv.f[1];
        }
      }
    }
  }

  // ---- LayerNorm over 128 cols (64-lane reduce) + store ----
  {
    F2 g2, bb2;
    g2.v = *(const float2*)(lng + ct * 2);
    bb2.v = *(const float2*)(lnb + ct * 2);
#pragma unroll
    for (int r = 0; r < TM; r++) {
      float s = af[r][0] + af[r][1];
      float q = af[r][0] * af[r][0] + af[r][1] * af[r][1];
#pragma unroll
      for (int off = 1; off <= 32; off <<= 1) {
        s += __shfl_xor(s, off);
        q += __shfl_xor(q, off);
      }
      const float mu = s * (1.0f / 128.0f);
      const float var = q * (1.0f / 128.0f) - mu * mu;
      const float rstd = rsqrtf(var + 1e-5f);
      F2 o;
      o.f[0] = (af[r][0] - mu) * rstd * g2.f[0] + bb2.f[0];
      o.f[1] = (af[r][1] - mu) * rstd * g2.f[1] + bb2.f[1];
      *(float2*)(out + (size_t)(r0 + mr + r) * 128 + ct * 2) = o.v;
    }
  }
}

extern "C" void kernel_launch(void* const* d_in, const int* in_sizes, int n_in,
                              void* d_out, int out_size, void* d_ws,
                              size_t ws_size, hipStream_t stream) {
  const float* node   = (const float*)d_in[0];
  const float* edge   = (const float*)d_in[1];
  const float* w_init = (const float*)d_in[2];
  const float* b_init = (const float*)d_in[3];
  const float* w_t0   = (const float*)d_in[4];
  const float* b_t0   = (const float*)d_in[5];
  const float* w_t1   = (const float*)d_in[6];
  const float* b_t1   = (const float*)d_in[7];
  const float* w_fin  = (const float*)d_in[8];
  const float* b_fin  = (const float*)d_in[9];
  const float* ln_g   = (const float*)d_in[10];
  const float* ln_b   = (const float*)d_in[11];
  float* out = (float*)d_out;

  // workspace: nb (256KB) | Pb (768KB) | Q (768KB)
  float* nb = (float*)d_ws;
  float* Pb = nb + 512 * 128;
  float* Qm = Pb + 512 * 384;

  node_proj<<<512, 128, 0, stream>>>(node, w_init, b_init, nb);
  pq_proj<<<512, 384, 0, stream>>>(nb, w_t0, b_t0, Pb, Qm);
  edge_fused<<<8192, 256, 0, stream>>>(edge, nb, Pb, Qm, w_t0, w_t1, b_t1,
                                       w_fin, b_fin, ln_g, ln_b, out);
}